// Round 16
// baseline (929.632 us; speedup 1.0000x reference)
//
#include <hip/hip_runtime.h>
#include <hip/hip_bf16.h>
#include <hip/hip_fp16.h>

#define VX 160
#define VY 160
#define VZ 32
#define NC 64
#define NPTS 200000
#define BN_EPS 1e-3f
#define YB 4                      // y-columns per conv block

typedef __attribute__((ext_vector_type(4))) float f32x4;
typedef __attribute__((ext_vector_type(8))) _Float16 f16x8;
typedef unsigned short u16;
typedef unsigned long long u64;

__device__ __forceinline__ float h2f(u16 u) {
    union { u16 s; _Float16 h; } v; v.s = u; return (float)v.h;
}
__device__ __forceinline__ u16 f2h(float f) {
    union { u16 s; _Float16 h; } v; v.h = (_Float16)f; return v.s;
}

// ------------------------------------------- scatter-mean (scaled) into f16 grid
__global__ __launch_bounds__(256) void k_scatter(const float* __restrict__ in,
                                                 const float* __restrict__ inv,
                                                 const int* __restrict__ vidx,
                                                 u64* __restrict__ vox) {
    int t = blockIdx.x * 256 + threadIdx.x;     // t < NPTS*16 exactly
    int n = t >> 4, q = t & 15;
    int vx = vidx[n * 3 + 0], vy = vidx[n * 3 + 1], vz = vidx[n * 3 + 2];
    int v = (vx * VY + vy) * VZ + vz;
    float s = inv[v];
    float4 a = *(const float4*)&in[n * NC + q * 4];
    float av0 = a.x * s, av1 = a.y * s, av2 = a.z * s, av3 = a.w * s;
    u64* addr = &vox[(size_t)v * 16 + q];
    u64 old = 0ull, assumed;
    do {
        assumed = old;
        union { u64 u; u16 h[4]; } cur, nxt;
        cur.u = assumed;
        nxt.h[0] = f2h(h2f(cur.h[0]) + av0);
        nxt.h[1] = f2h(h2f(cur.h[1]) + av1);
        nxt.h[2] = f2h(h2f(cur.h[2]) + av2);
        nxt.h[3] = f2h(h2f(cur.h[3]) + av3);
        old = atomicCAS(addr, assumed, nxt.u);
    } while (old != assumed);
}

// --------------------------------------------- weights: f32 [tap][ci][co] -> f16 [tap][co][ci]
__global__ __launch_bounds__(256) void k_wt(const float* __restrict__ w,
                                            u16* __restrict__ wT) {
    int t = blockIdx.x * 256 + threadIdx.x;
    if (t >= 27 * NC * NC) return;
    int tap = t / (NC * NC), r = t % (NC * NC);
    int co = r / NC, ci = r % NC;
    wT[t] = f2h(w[(tap * NC + ci) * NC + co]);
}

#define MFMA16(a, b, c) __builtin_amdgcn_mfma_f32_16x16x32_f16((a), (b), (c), 0, 0, 0)

// ---------------------------------------------------------------- conv3d MFMA
// BARRIER-FREE: A-fragments are read directly from the global f16 grid (L2/L3
// resident; layout (x,y,z,ci) makes each fragment 16B contiguous, a wave's
// a0+a1 cover a contiguous 2KB). No LDS staging, no main-loop __syncthreads ->
// waves are independent and TLP (4 waves/SIMD at VGPR<=128) hides L2 latency.
// OOB (x/y/z pad) handled by per-lane pointer-select to a 4KB zero page.
// Block: M = 4y x 32z, N = 64 co; 4 waves as in r11 (wave = 2y x 2zh x 2nt).
__global__ __launch_bounds__(256, 2) void k_conv(const u16* __restrict__ vox,
                                                 const u16* __restrict__ wT,
                                                 const u16* __restrict__ zpg,
                                                 const float* __restrict__ bias,
                                                 const float* __restrict__ g2,
                                                 const float* __restrict__ b2,
                                                 const float* __restrict__ m2,
                                                 const float* __restrict__ v2,
                                                 u16* __restrict__ outb) {
    __shared__ __align__(16) u16 ebuf[YB * VZ * NC];     // 16,384 B (epilogue only)
    // XCD-aware bijective swizzle: 6400 = 8 XCDs x 800
    int bx0 = blockIdx.x;
    int bx = (bx0 & 7) * 800 + (bx0 >> 3);
    int x = bx / (VY / YB), y0 = (bx % (VY / YB)) * YB;
    int tid = threadIdx.x;
    int wave = tid >> 6, l = tid & 63;
    int yw = (wave >> 1) * 2;            // local y base of this wave (0 or 2)
    int nh = wave & 1;                   // co half (0/1)
    int lr = l & 15;
    int kg = l >> 4;                     // 0..3
    int lane_off = lr * NC + kg * 8;     // u16 offset of this lane's fragment in a z-run
    const u16* zp_lane = zpg + l * 8;    // per-lane slot in the zero page

    f32x4 acc[4][2];
    #pragma unroll
    for (int m = 0; m < 4; ++m)
        #pragma unroll
        for (int nt = 0; nt < 2; ++nt) acc[m][nt] = (f32x4){0.f, 0.f, 0.f, 0.f};

    // B prefetch for tap 0 (q = nt*2 + kf)
    f16x8 bc[4], bn[4];
    #pragma unroll
    for (int q = 0; q < 4; ++q)
        bc[q] = *(const f16x8*)&wT[(nh * 32 + (q >> 1) * 16 + lr) * NC + (q & 1) * 32 + kg * 8];

    for (int cx = 0; cx < 3; ++cx) {
        int xp = x + cx - 1;
        bool xok = (unsigned)xp < VX;
        const u16* xbase = vox + (size_t)xp * (VY * VZ * NC);
        #pragma unroll
        for (int t9 = 0; t9 < 9; ++t9) {
            const int dy = t9 / 3, dz = t9 % 3;          // compile-time constants
            bool more = (cx < 2) || (t9 < 8);
            if (more) {
                const u16* wb = &wT[(cx * 9 + t9 + 1) * (NC * NC)];
                #pragma unroll
                for (int q = 0; q < 4; ++q)
                    bn[q] = *(const f16x8*)&wb[(nh * 32 + (q >> 1) * 16 + lr) * NC + (q & 1) * 32 + kg * 8];
            }
            // A fragments: direct global reads with zero-page OOB select
            f16x8 a[8];
            #pragma unroll
            for (int m = 0; m < 4; ++m) {
                const int jy = m >> 1, zh = m & 1;
                const int zb = zh * 16 + dz - 1;         // lane z = zb + lr
                int yp = y0 + yw + jy + dy - 1;
                bool ok = xok && ((unsigned)yp < VY) && ((unsigned)(zb + lr) < VZ);
                const u16* rp = xbase + (yp * VZ + zb) * NC + lane_off;
                const u16* p = ok ? rp : zp_lane;
                a[2 * m]     = *(const f16x8*)p;
                a[2 * m + 1] = *(const f16x8*)(p + 32);
            }
            #pragma unroll
            for (int m = 0; m < 4; ++m) {
                acc[m][0] = MFMA16(a[2 * m],     bc[0], acc[m][0]);
                acc[m][0] = MFMA16(a[2 * m + 1], bc[1], acc[m][0]);
                acc[m][1] = MFMA16(a[2 * m],     bc[2], acc[m][1]);
                acc[m][1] = MFMA16(a[2 * m + 1], bc[3], acc[m][1]);
            }
            if (more) {
                #pragma unroll
                for (int q = 0; q < 4; ++q) bc[q] = bn[q];
            }
        }
    }

    // ---------------- epilogue: BN fold, stage f16 result in LDS, coalesced store
    float s[2], o[2], bb[2];
    #pragma unroll
    for (int nt = 0; nt < 2; ++nt) {
        int co = nh * 32 + nt * 16 + lr;
        s[nt] = g2[co] * rsqrtf(v2[co] + BN_EPS);
        o[nt] = b2[co] - m2[co] * s[nt];
        bb[nt] = bias[co];
    }
    #pragma unroll
    for (int m = 0; m < 4; ++m) {
        int jy = m >> 1, zh = m & 1;
        int yl = yw + jy;                // 0..3
        #pragma unroll
        for (int nt = 0; nt < 2; ++nt) {
            int co = nh * 32 + nt * 16 + lr;
            #pragma unroll
            for (int rr = 0; rr < 4; ++rr) {
                int z = zh * 16 + kg * 4 + rr;       // D row = (lane>>4)*4 + reg
                ebuf[(yl * 32 + z) * 64 + co] =
                    f2h(fmaxf(acc[m][nt][rr] + bb[nt], 0.f) * s[nt] + o[nt]);
            }
        }
    }
    __syncthreads();
    u16* ob = &outb[(size_t)((x * VY + y0) * VZ) * NC];
    #pragma unroll
    for (int i = 0; i < 4; ++i) {        // 4y*32z*64c*2B = 16 KB, fully coalesced
        int idx = tid + i * 256;
        *(uint4*)&ob[idx * 8] = *(const uint4*)&ebuf[idx * 8];
    }
}

// --------------------------------------- MLP+BN1 + trilinear devoxelize + add
__global__ __launch_bounds__(256) void k_final(const float* __restrict__ in,
                                               const float* __restrict__ pts,
                                               const float* __restrict__ Wm,
                                               const float* __restrict__ bm,
                                               const float* __restrict__ g1,
                                               const float* __restrict__ be1,
                                               const float* __restrict__ m1,
                                               const float* __restrict__ v1,
                                               const u16* __restrict__ convb,
                                               float* __restrict__ out) {
    __shared__ float sfeat[4][NC];
    int tid = threadIdx.x;
    int co = tid & 63;
    int p = blockIdx.x * 4 + (tid >> 6);           // exact: 50000*4 = NPTS
    sfeat[tid >> 6][co] = in[p * NC + co];
    __syncthreads();

    float acc = bm[co];
    const float* sr = sfeat[tid >> 6];
    #pragma unroll 8
    for (int ci = 0; ci < NC; ++ci)
        acc = fmaf(sr[ci], Wm[ci * NC + co], acc);
    acc = fmaxf(acc, 0.f);
    float s1 = g1[co] * rsqrtf(v1[co] + BN_EPS);
    float mlp = (acc - m1[co]) * s1 + be1[co];

    float px = fminf(fmaxf(pts[p * 3 + 0], 0.f), (float)(VX - 1));
    float py = fminf(fmaxf(pts[p * 3 + 1], 0.f), (float)(VY - 1));
    float pz = fminf(fmaxf(pts[p * 3 + 2], 0.f), (float)(VZ - 1));
    float fx = floorf(px), fy = floorf(py), fz = floorf(pz);
    int ix0 = (int)fx, iy0 = (int)fy, iz0 = (int)fz;
    int ix1 = min(ix0 + 1, VX - 1), iy1 = min(iy0 + 1, VY - 1), iz1 = min(iz0 + 1, VZ - 1);
    float wx1 = px - fx, wy1 = py - fy, wz1 = pz - fz;
    float wx0 = 1.f - wx1, wy0 = 1.f - wy1, wz0 = 1.f - wz1;

    #define CORNER(ix, iy, iz) h2f(convb[(((ix) * VY + (iy)) * VZ + (iz)) * NC + co])
    float t = 0.f;
    t = fmaf(CORNER(ix0, iy0, iz0), wx0 * wy0 * wz0, t);
    t = fmaf(CORNER(ix0, iy0, iz1), wx0 * wy0 * wz1, t);
    t = fmaf(CORNER(ix0, iy1, iz0), wx0 * wy1 * wz0, t);
    t = fmaf(CORNER(ix0, iy1, iz1), wx0 * wy1 * wz1, t);
    t = fmaf(CORNER(ix1, iy0, iz0), wx1 * wy0 * wz0, t);
    t = fmaf(CORNER(ix1, iy0, iz1), wx1 * wy0 * wz1, t);
    t = fmaf(CORNER(ix1, iy1, iz0), wx1 * wy1 * wz0, t);
    t = fmaf(CORNER(ix1, iy1, iz1), wx1 * wy1 * wz1, t);
    #undef CORNER

    out[p * NC + co] = mlp + t;
}

extern "C" void kernel_launch(void* const* d_in, const int* in_sizes, int n_in,
                              void* d_out, int out_size, void* d_ws, size_t ws_size,
                              hipStream_t stream) {
    const float* inputs    = (const float*)d_in[0];
    const float* pt_coords = (const float*)d_in[1];
    const float* ppv_inv   = (const float*)d_in[2];
    const float* W_mlp     = (const float*)d_in[3];
    const float* b_mlp     = (const float*)d_in[4];
    const float* gamma1    = (const float*)d_in[5];
    const float* beta1     = (const float*)d_in[6];
    const float* mean1     = (const float*)d_in[7];
    const float* var1      = (const float*)d_in[8];
    const float* conv_w    = (const float*)d_in[9];
    const float* conv_b    = (const float*)d_in[10];
    const float* gamma2    = (const float*)d_in[11];
    const float* beta2     = (const float*)d_in[12];
    const float* mean2     = (const float*)d_in[13];
    const float* var2      = (const float*)d_in[14];
    const int*   vidx      = (const int*)d_in[15];

    const size_t NVOX = (size_t)VX * VY * VZ;                // 819,200
    char* ws = (char*)d_ws;
    u16* vox   = (u16*)ws;                                   // 104,857,600 B (f16 scaled grid)
    u16* convo = (u16*)(ws + NVOX * NC * 2);                 // 104,857,600 B (f16 conv out)
    u16* wT    = (u16*)(ws + 2 * NVOX * NC * 2);             // 221,184 B
    u16* zpg   = (u16*)(ws + 2 * NVOX * NC * 2 + 221184);    // 4,096 B zero page
    float* out = (float*)d_out;

    hipMemsetAsync(vox, 0, NVOX * NC * 2, stream);
    hipMemsetAsync(zpg, 0, 4096, stream);
    k_wt<<<432, 256, 0, stream>>>(conv_w, wT);
    k_scatter<<<(NPTS * 16) / 256, 256, 0, stream>>>(inputs, ppv_inv, vidx, (u64*)vox);
    k_conv<<<VX * (VY / YB), 256, 0, stream>>>(vox, wT, zpg, conv_b, gamma2, beta2, mean2, var2, convo);
    k_final<<<NPTS / 4, 256, 0, stream>>>(inputs, pt_coords, W_mlp, b_mlp,
                                          gamma1, beta1, mean1, var1, convo, out);
}

// Round 17
// 556.585 us; speedup vs baseline: 1.6702x; 1.6702x over previous
//
#include <hip/hip_runtime.h>
#include <hip/hip_bf16.h>
#include <hip/hip_fp16.h>

#define VX 160
#define VY 160
#define VZ 32
#define NC 64
#define NPTS 200000
#define BN_EPS 1e-3f
#define YB 4                      // y-columns per conv block
#define SLAB_ROWS ((YB + 2) * 34) // 204 rows (y-major, z-padded)

typedef __attribute__((ext_vector_type(4))) float f32x4;
typedef __attribute__((ext_vector_type(8))) _Float16 f16x8;
typedef unsigned short u16;
typedef unsigned long long u64;

__device__ __forceinline__ float h2f(u16 u) {
    union { u16 s; _Float16 h; } v; v.s = u; return (float)v.h;
}
__device__ __forceinline__ u16 f2h(float f) {
    union { u16 s; _Float16 h; } v; v.h = (_Float16)f; return v.s;
}

// ------------------------------------------- scatter-mean (scaled) into f16 grid
__global__ __launch_bounds__(256) void k_scatter(const float* __restrict__ in,
                                                 const float* __restrict__ inv,
                                                 const int* __restrict__ vidx,
                                                 u64* __restrict__ vox) {
    int t = blockIdx.x * 256 + threadIdx.x;     // t < NPTS*16 exactly
    int n = t >> 4, q = t & 15;
    int vx = vidx[n * 3 + 0], vy = vidx[n * 3 + 1], vz = vidx[n * 3 + 2];
    int v = (vx * VY + vy) * VZ + vz;
    float s = inv[v];
    float4 a = *(const float4*)&in[n * NC + q * 4];
    float av0 = a.x * s, av1 = a.y * s, av2 = a.z * s, av3 = a.w * s;
    u64* addr = &vox[(size_t)v * 16 + q];
    u64 old = 0ull, assumed;
    do {
        assumed = old;
        union { u64 u; u16 h[4]; } cur, nxt;
        cur.u = assumed;
        nxt.h[0] = f2h(h2f(cur.h[0]) + av0);
        nxt.h[1] = f2h(h2f(cur.h[1]) + av1);
        nxt.h[2] = f2h(h2f(cur.h[2]) + av2);
        nxt.h[3] = f2h(h2f(cur.h[3]) + av3);
        old = atomicCAS(addr, assumed, nxt.u);
    } while (old != assumed);
}

// --------------------------------------------- weights: f32 [tap][ci][co] -> f16 [tap][co][ci]
__global__ __launch_bounds__(256) void k_wt(const float* __restrict__ w,
                                            u16* __restrict__ wT) {
    int t = blockIdx.x * 256 + threadIdx.x;
    if (t >= 27 * NC * NC) return;
    int tap = t / (NC * NC), r = t % (NC * NC);
    int co = r / NC, ci = r % NC;
    wT[t] = f2h(w[(tap * NC + ci) * NC + co]);
}

#define MFMA16(a, b, c) __builtin_amdgcn_mfma_f32_16x16x32_f16((a), (b), (c), 0, 0, 0)

// ---------------------------------------------------------------- conv3d MFMA
// r13 champion + (1) x-fastest XCD tile order: consecutive blocks in an XCD
// share 2 of 3 slab planes -> stage hits L2 (~200cy) instead of L3 (~500cy);
// (2) s_setprio(1) around the MFMA burst (blocks at independent phases).
__global__ __launch_bounds__(256, 2) void k_conv(const u16* __restrict__ vox,
                                                 const u16* __restrict__ wT,
                                                 const float* __restrict__ bias,
                                                 const float* __restrict__ g2,
                                                 const float* __restrict__ b2,
                                                 const float* __restrict__ m2,
                                                 const float* __restrict__ v2,
                                                 u16* __restrict__ outb) {
    __shared__ __align__(16) u16 tile[SLAB_ROWS * 64];   // 26,112 B
    // XCD-aware bijective mapping, x fastest: 6400 = 8 XCDs x (40 ychunks x 20 x)
    int bx0 = blockIdx.x;
    int xcd = bx0 & 7, r8 = bx0 >> 3;          // r8 in [0,800)
    int x = xcd * 20 + (r8 % 20);
    int y0 = (r8 / 20) * YB;
    int tid = threadIdx.x;
    int wave = tid >> 6, l = tid & 63;
    int yw = (wave >> 1) * 2;            // local y base of this wave (0 or 2)
    int nh = wave & 1;                   // co half (0/1)
    int lr = l & 15;
    int kg = l >> 4;                     // 0..3

    f32x4 acc[4][2];
    #pragma unroll
    for (int m = 0; m < 4; ++m)
        #pragma unroll
        for (int nt = 0; nt < 2; ++nt) acc[m][nt] = (f32x4){0.f, 0.f, 0.f, 0.f};

    // prefetch B for tap 0 (q = nt*2 + kf)
    f16x8 bc[4], bn[4];
    #pragma unroll
    for (int q = 0; q < 4; ++q)
        bc[q] = *(const f16x8*)&wT[(nh * 32 + (q >> 1) * 16 + lr) * NC + (q & 1) * 32 + kg * 8];

    for (int cx = 0; cx < 3; ++cx) {
        __syncthreads();                 // protect previous slab reads
        int xx = x + cx - 1;
        bool xok = (unsigned)xx < VX;
        #pragma unroll
        for (int i = 0; i < 7; ++i) {    // ceil(204*8 / 256) = 7
            int G = tid + i * 256;
            if (G < SLAB_ROWS * 8) {
                int r = G >> 3, g = G & 7;
                int yl = r / 34, zp = r - yl * 34;
                int y = y0 + yl - 1;
                uint4 val = make_uint4(0u, 0u, 0u, 0u);
                if (xok && zp >= 1 && zp <= 32 && (unsigned)y < VY)
                    val = *(const uint4*)&vox[(size_t)(((xx * VY) + y) * VZ + (zp - 1)) * NC + g * 8];
                *(uint4*)&tile[r * 64 + (g ^ (r & 7)) * 8] = val;
            }
        }
        __syncthreads();

        #pragma unroll
        for (int t9 = 0; t9 < 9; ++t9) {
            const int dy = t9 / 3, dz = t9 % 3;          // constants (unrolled)
            bool more = (cx < 2) || (t9 < 8);
            if (more) {
                const u16* wb = &wT[(cx * 9 + t9 + 1) * (NC * NC)];
                #pragma unroll
                for (int q = 0; q < 4; ++q)
                    bn[q] = *(const f16x8*)&wb[(nh * 32 + (q >> 1) * 16 + lr) * NC + (q & 1) * 32 + kg * 8];
            }
            int rbase = (yw + dy) * 34 + lr + dz;
            // deep A-prefetch: all 8 fragments issued back-to-back
            f16x8 a[8];
            #pragma unroll
            for (int m = 0; m < 4; ++m) {                // rn = rbase + jy*34 + zh*16
                int rn = rbase + (m >> 1) * 34 + (m & 1) * 16;
                int sw = rn & 7;
                a[2 * m]     = *(const f16x8*)&tile[rn * 64 + ((kg ^ sw) * 8)];
                a[2 * m + 1] = *(const f16x8*)&tile[rn * 64 + (((4 + kg) ^ sw) * 8)];
            }
            __builtin_amdgcn_s_setprio(1);
            #pragma unroll
            for (int m = 0; m < 4; ++m) {
                acc[m][0] = MFMA16(a[2 * m],     bc[0], acc[m][0]);
                acc[m][0] = MFMA16(a[2 * m + 1], bc[1], acc[m][0]);
                acc[m][1] = MFMA16(a[2 * m],     bc[2], acc[m][1]);
                acc[m][1] = MFMA16(a[2 * m + 1], bc[3], acc[m][1]);
            }
            __builtin_amdgcn_s_setprio(0);
            if (more) {
                #pragma unroll
                for (int q = 0; q < 4; ++q) bc[q] = bn[q];
            }
        }
    }

    // ---------------- epilogue: BN fold, stage f16 result in LDS, coalesced store
    float s[2], o[2], bb[2];
    #pragma unroll
    for (int nt = 0; nt < 2; ++nt) {
        int co = nh * 32 + nt * 16 + lr;
        s[nt] = g2[co] * rsqrtf(v2[co] + BN_EPS);
        o[nt] = b2[co] - m2[co] * s[nt];
        bb[nt] = bias[co];
    }
    __syncthreads();                     // all slab reads done; reuse tile
    #pragma unroll
    for (int m = 0; m < 4; ++m) {
        int jy = m >> 1, zh = m & 1;
        int yl = yw + jy;                // 0..3
        #pragma unroll
        for (int nt = 0; nt < 2; ++nt) {
            int co = nh * 32 + nt * 16 + lr;
            #pragma unroll
            for (int rr = 0; rr < 4; ++rr) {
                int z = zh * 16 + kg * 4 + rr;       // D row = (lane>>4)*4 + reg
                tile[(yl * 32 + z) * 64 + co] =
                    f2h(fmaxf(acc[m][nt][rr] + bb[nt], 0.f) * s[nt] + o[nt]);
            }
        }
    }
    __syncthreads();
    u16* ob = &outb[(size_t)((x * VY + y0) * VZ) * NC];
    #pragma unroll
    for (int i = 0; i < 4; ++i) {        // 4y*32z*64c*2B = 16 KB, fully coalesced
        int idx = tid + i * 256;
        *(uint4*)&ob[idx * 8] = *(const uint4*)&tile[idx * 8];
    }
}

// --------------------------------------- MLP+BN1 + trilinear devoxelize + add
__global__ __launch_bounds__(256) void k_final(const float* __restrict__ in,
                                               const float* __restrict__ pts,
                                               const float* __restrict__ Wm,
                                               const float* __restrict__ bm,
                                               const float* __restrict__ g1,
                                               const float* __restrict__ be1,
                                               const float* __restrict__ m1,
                                               const float* __restrict__ v1,
                                               const u16* __restrict__ convb,
                                               float* __restrict__ out) {
    __shared__ float sfeat[4][NC];
    int tid = threadIdx.x;
    int co = tid & 63;
    int p = blockIdx.x * 4 + (tid >> 6);           // exact: 50000*4 = NPTS
    sfeat[tid >> 6][co] = in[p * NC + co];
    __syncthreads();

    float acc = bm[co];
    const float* sr = sfeat[tid >> 6];
    #pragma unroll 8
    for (int ci = 0; ci < NC; ++ci)
        acc = fmaf(sr[ci], Wm[ci * NC + co], acc);
    acc = fmaxf(acc, 0.f);
    float s1 = g1[co] * rsqrtf(v1[co] + BN_EPS);
    float mlp = (acc - m1[co]) * s1 + be1[co];

    float px = fminf(fmaxf(pts[p * 3 + 0], 0.f), (float)(VX - 1));
    float py = fminf(fmaxf(pts[p * 3 + 1], 0.f), (float)(VY - 1));
    float pz = fminf(fmaxf(pts[p * 3 + 2], 0.f), (float)(VZ - 1));
    float fx = floorf(px), fy = floorf(py), fz = floorf(pz);
    int ix0 = (int)fx, iy0 = (int)fy, iz0 = (int)fz;
    int ix1 = min(ix0 + 1, VX - 1), iy1 = min(iy0 + 1, VY - 1), iz1 = min(iz0 + 1, VZ - 1);
    float wx1 = px - fx, wy1 = py - fy, wz1 = pz - fz;
    float wx0 = 1.f - wx1, wy0 = 1.f - wy1, wz0 = 1.f - wz1;

    #define CORNER(ix, iy, iz) h2f(convb[(((ix) * VY + (iy)) * VZ + (iz)) * NC + co])
    float t = 0.f;
    t = fmaf(CORNER(ix0, iy0, iz0), wx0 * wy0 * wz0, t);
    t = fmaf(CORNER(ix0, iy0, iz1), wx0 * wy0 * wz1, t);
    t = fmaf(CORNER(ix0, iy1, iz0), wx0 * wy1 * wz0, t);
    t = fmaf(CORNER(ix0, iy1, iz1), wx0 * wy1 * wz1, t);
    t = fmaf(CORNER(ix1, iy0, iz0), wx1 * wy0 * wz0, t);
    t = fmaf(CORNER(ix1, iy0, iz1), wx1 * wy0 * wz1, t);
    t = fmaf(CORNER(ix1, iy1, iz0), wx1 * wy1 * wz0, t);
    t = fmaf(CORNER(ix1, iy1, iz1), wx1 * wy1 * wz1, t);
    #undef CORNER

    out[p * NC + co] = mlp + t;
}

extern "C" void kernel_launch(void* const* d_in, const int* in_sizes, int n_in,
                              void* d_out, int out_size, void* d_ws, size_t ws_size,
                              hipStream_t stream) {
    const float* inputs    = (const float*)d_in[0];
    const float* pt_coords = (const float*)d_in[1];
    const float* ppv_inv   = (const float*)d_in[2];
    const float* W_mlp     = (const float*)d_in[3];
    const float* b_mlp     = (const float*)d_in[4];
    const float* gamma1    = (const float*)d_in[5];
    const float* beta1     = (const float*)d_in[6];
    const float* mean1     = (const float*)d_in[7];
    const float* var1      = (const float*)d_in[8];
    const float* conv_w    = (const float*)d_in[9];
    const float* conv_b    = (const float*)d_in[10];
    const float* gamma2    = (const float*)d_in[11];
    const float* beta2     = (const float*)d_in[12];
    const float* mean2     = (const float*)d_in[13];
    const float* var2      = (const float*)d_in[14];
    const int*   vidx      = (const int*)d_in[15];

    const size_t NVOX = (size_t)VX * VY * VZ;                // 819,200
    char* ws = (char*)d_ws;
    u16* vox   = (u16*)ws;                                   // 104,857,600 B (f16 scaled grid)
    u16* convo = (u16*)(ws + NVOX * NC * 2);                 // 104,857,600 B (f16 conv out)
    u16* wT    = (u16*)(ws + 2 * NVOX * NC * 2);             // 221,184 B
    float* out = (float*)d_out;

    hipMemsetAsync(vox, 0, NVOX * NC * 2, stream);
    k_wt<<<432, 256, 0, stream>>>(conv_w, wT);
    k_scatter<<<(NPTS * 16) / 256, 256, 0, stream>>>(inputs, ppv_inv, vidx, (u64*)vox);
    k_conv<<<VX * (VY / YB), 256, 0, stream>>>(vox, wT, conv_b, gamma2, beta2, mean2, var2, convo);
    k_final<<<NPTS / 4, 256, 0, stream>>>(inputs, pt_coords, W_mlp, b_mlp,
                                          gamma1, beta1, mean1, var1, convo, out);
}

// Round 18
// 536.172 us; speedup vs baseline: 1.7338x; 1.0381x over previous
//
#include <hip/hip_runtime.h>
#include <hip/hip_bf16.h>
#include <hip/hip_fp16.h>

#define VX 160
#define VY 160
#define VZ 32
#define NC 64
#define NPTS 200000
#define BN_EPS 1e-3f
#define YB 4                      // y-columns per conv block
#define SLAB_ROWS ((YB + 2) * 34) // 204 rows (y-major, z-padded)

typedef __attribute__((ext_vector_type(4))) float f32x4;
typedef __attribute__((ext_vector_type(8))) _Float16 f16x8;
typedef unsigned short u16;
typedef unsigned long long u64;

__device__ __forceinline__ float h2f(u16 u) {
    union { u16 s; _Float16 h; } v; v.s = u; return (float)v.h;
}
__device__ __forceinline__ u16 f2h(float f) {
    union { u16 s; _Float16 h; } v; v.h = (_Float16)f; return v.s;
}

// ------------------------------------------- scatter-mean (scaled) into f16 grid
// Fast path: inv[v]==1.0f <=> exactly one point in voxel v <=> sole writer ->
// plain 8B store (no atomic). ~89% of points. Multi-point voxels use CAS.
__global__ __launch_bounds__(256) void k_scatter(const float* __restrict__ in,
                                                 const float* __restrict__ inv,
                                                 const int* __restrict__ vidx,
                                                 u64* __restrict__ vox) {
    int t = blockIdx.x * 256 + threadIdx.x;     // t < NPTS*16 exactly
    int n = t >> 4, q = t & 15;
    int vx = vidx[n * 3 + 0], vy = vidx[n * 3 + 1], vz = vidx[n * 3 + 2];
    int v = (vx * VY + vy) * VZ + vz;
    float s = inv[v];
    float4 a = *(const float4*)&in[n * NC + q * 4];
    float av0 = a.x * s, av1 = a.y * s, av2 = a.z * s, av3 = a.w * s;
    u64* addr = &vox[(size_t)v * 16 + q];
    union { u64 u; u16 h[4]; } pk;
    pk.h[0] = f2h(av0); pk.h[1] = f2h(av1); pk.h[2] = f2h(av2); pk.h[3] = f2h(av3);
    if (s == 1.0f) {                            // singleton voxel: sole writer
        *addr = pk.u;
        return;
    }
    u64 old = 0ull, assumed;
    do {
        assumed = old;
        union { u64 u; u16 h[4]; } cur, nxt;
        cur.u = assumed;
        nxt.h[0] = f2h(h2f(cur.h[0]) + av0);
        nxt.h[1] = f2h(h2f(cur.h[1]) + av1);
        nxt.h[2] = f2h(h2f(cur.h[2]) + av2);
        nxt.h[3] = f2h(h2f(cur.h[3]) + av3);
        old = atomicCAS(addr, assumed, nxt.u);
    } while (old != assumed);
}

// --------------------------------------------- weights: f32 [tap][ci][co] -> f16 [tap][co][ci]
__global__ __launch_bounds__(256) void k_wt(const float* __restrict__ w,
                                            u16* __restrict__ wT) {
    int t = blockIdx.x * 256 + threadIdx.x;
    if (t >= 27 * NC * NC) return;
    int tap = t / (NC * NC), r = t % (NC * NC);
    int co = r / NC, ci = r % NC;
    wT[t] = f2h(w[(tap * NC + ci) * NC + co]);
}

#define MFMA16(a, b, c) __builtin_amdgcn_mfma_f32_16x16x32_f16((a), (b), (c), 0, 0, 0)

// ---------------------------------------------------------------- conv3d MFMA
// r13 champion, verbatim. Thin-wave (r11) + deep A-prefetch: all 8 A-fragments
// of a tap issued back-to-back before the 16-MFMA burst. VGPR 88, 26.1KB LDS.
__global__ __launch_bounds__(256, 2) void k_conv(const u16* __restrict__ vox,
                                                 const u16* __restrict__ wT,
                                                 const float* __restrict__ bias,
                                                 const float* __restrict__ g2,
                                                 const float* __restrict__ b2,
                                                 const float* __restrict__ m2,
                                                 const float* __restrict__ v2,
                                                 u16* __restrict__ outb) {
    __shared__ __align__(16) u16 tile[SLAB_ROWS * 64];   // 26,112 B
    // XCD-aware bijective swizzle: 6400 = 8 XCDs x 800
    int bx0 = blockIdx.x;
    int bx = (bx0 & 7) * 800 + (bx0 >> 3);
    int x = bx / (VY / YB), y0 = (bx % (VY / YB)) * YB;
    int tid = threadIdx.x;
    int wave = tid >> 6, l = tid & 63;
    int yw = (wave >> 1) * 2;            // local y base of this wave (0 or 2)
    int nh = wave & 1;                   // co half (0/1)
    int lr = l & 15;
    int kg = l >> 4;                     // 0..3

    f32x4 acc[4][2];
    #pragma unroll
    for (int m = 0; m < 4; ++m)
        #pragma unroll
        for (int nt = 0; nt < 2; ++nt) acc[m][nt] = (f32x4){0.f, 0.f, 0.f, 0.f};

    // prefetch B for tap 0 (q = nt*2 + kf)
    f16x8 bc[4], bn[4];
    #pragma unroll
    for (int q = 0; q < 4; ++q)
        bc[q] = *(const f16x8*)&wT[(nh * 32 + (q >> 1) * 16 + lr) * NC + (q & 1) * 32 + kg * 8];

    for (int cx = 0; cx < 3; ++cx) {
        __syncthreads();                 // protect previous slab reads
        int xx = x + cx - 1;
        bool xok = (unsigned)xx < VX;
        #pragma unroll
        for (int i = 0; i < 7; ++i) {    // ceil(204*8 / 256) = 7
            int G = tid + i * 256;
            if (G < SLAB_ROWS * 8) {
                int r = G >> 3, g = G & 7;
                int yl = r / 34, zp = r - yl * 34;
                int y = y0 + yl - 1;
                uint4 val = make_uint4(0u, 0u, 0u, 0u);
                if (xok && zp >= 1 && zp <= 32 && (unsigned)y < VY)
                    val = *(const uint4*)&vox[(size_t)(((xx * VY) + y) * VZ + (zp - 1)) * NC + g * 8];
                *(uint4*)&tile[r * 64 + (g ^ (r & 7)) * 8] = val;
            }
        }
        __syncthreads();

        #pragma unroll
        for (int t9 = 0; t9 < 9; ++t9) {
            const int dy = t9 / 3, dz = t9 % 3;          // constants (unrolled)
            bool more = (cx < 2) || (t9 < 8);
            if (more) {
                const u16* wb = &wT[(cx * 9 + t9 + 1) * (NC * NC)];
                #pragma unroll
                for (int q = 0; q < 4; ++q)
                    bn[q] = *(const f16x8*)&wb[(nh * 32 + (q >> 1) * 16 + lr) * NC + (q & 1) * 32 + kg * 8];
            }
            int rbase = (yw + dy) * 34 + lr + dz;
            // deep A-prefetch: all 8 fragments issued back-to-back
            f16x8 a[8];
            #pragma unroll
            for (int m = 0; m < 4; ++m) {                // rn = rbase + jy*34 + zh*16
                int rn = rbase + (m >> 1) * 34 + (m & 1) * 16;
                int sw = rn & 7;
                a[2 * m]     = *(const f16x8*)&tile[rn * 64 + ((kg ^ sw) * 8)];
                a[2 * m + 1] = *(const f16x8*)&tile[rn * 64 + (((4 + kg) ^ sw) * 8)];
            }
            #pragma unroll
            for (int m = 0; m < 4; ++m) {
                acc[m][0] = MFMA16(a[2 * m],     bc[0], acc[m][0]);
                acc[m][0] = MFMA16(a[2 * m + 1], bc[1], acc[m][0]);
                acc[m][1] = MFMA16(a[2 * m],     bc[2], acc[m][1]);
                acc[m][1] = MFMA16(a[2 * m + 1], bc[3], acc[m][1]);
            }
            if (more) {
                #pragma unroll
                for (int q = 0; q < 4; ++q) bc[q] = bn[q];
            }
        }
    }

    // ---------------- epilogue: BN fold, stage f16 result in LDS, coalesced store
    float s[2], o[2], bb[2];
    #pragma unroll
    for (int nt = 0; nt < 2; ++nt) {
        int co = nh * 32 + nt * 16 + lr;
        s[nt] = g2[co] * rsqrtf(v2[co] + BN_EPS);
        o[nt] = b2[co] - m2[co] * s[nt];
        bb[nt] = bias[co];
    }
    __syncthreads();                     // all slab reads done; reuse tile
    #pragma unroll
    for (int m = 0; m < 4; ++m) {
        int jy = m >> 1, zh = m & 1;
        int yl = yw + jy;                // 0..3
        #pragma unroll
        for (int nt = 0; nt < 2; ++nt) {
            int co = nh * 32 + nt * 16 + lr;
            #pragma unroll
            for (int rr = 0; rr < 4; ++rr) {
                int z = zh * 16 + kg * 4 + rr;       // D row = (lane>>4)*4 + reg
                tile[(yl * 32 + z) * 64 + co] =
                    f2h(fmaxf(acc[m][nt][rr] + bb[nt], 0.f) * s[nt] + o[nt]);
            }
        }
    }
    __syncthreads();
    u16* ob = &outb[(size_t)((x * VY + y0) * VZ) * NC];
    #pragma unroll
    for (int i = 0; i < 4; ++i) {        // 4y*32z*64c*2B = 16 KB, fully coalesced
        int idx = tid + i * 256;
        *(uint4*)&ob[idx * 8] = *(const uint4*)&tile[idx * 8];
    }
}

// --------------------------------------- MLP+BN1 + trilinear devoxelize + add
__global__ __launch_bounds__(256) void k_final(const float* __restrict__ in,
                                               const float* __restrict__ pts,
                                               const float* __restrict__ Wm,
                                               const float* __restrict__ bm,
                                               const float* __restrict__ g1,
                                               const float* __restrict__ be1,
                                               const float* __restrict__ m1,
                                               const float* __restrict__ v1,
                                               const u16* __restrict__ convb,
                                               float* __restrict__ out) {
    __shared__ float sfeat[4][NC];
    int tid = threadIdx.x;
    int co = tid & 63;
    int p = blockIdx.x * 4 + (tid >> 6);           // exact: 50000*4 = NPTS
    sfeat[tid >> 6][co] = in[p * NC + co];
    __syncthreads();

    float acc = bm[co];
    const float* sr = sfeat[tid >> 6];
    #pragma unroll 8
    for (int ci = 0; ci < NC; ++ci)
        acc = fmaf(sr[ci], Wm[ci * NC + co], acc);
    acc = fmaxf(acc, 0.f);
    float s1 = g1[co] * rsqrtf(v1[co] + BN_EPS);
    float mlp = (acc - m1[co]) * s1 + be1[co];

    float px = fminf(fmaxf(pts[p * 3 + 0], 0.f), (float)(VX - 1));
    float py = fminf(fmaxf(pts[p * 3 + 1], 0.f), (float)(VY - 1));
    float pz = fminf(fmaxf(pts[p * 3 + 2], 0.f), (float)(VZ - 1));
    float fx = floorf(px), fy = floorf(py), fz = floorf(pz);
    int ix0 = (int)fx, iy0 = (int)fy, iz0 = (int)fz;
    int ix1 = min(ix0 + 1, VX - 1), iy1 = min(iy0 + 1, VY - 1), iz1 = min(iz0 + 1, VZ - 1);
    float wx1 = px - fx, wy1 = py - fy, wz1 = pz - fz;
    float wx0 = 1.f - wx1, wy0 = 1.f - wy1, wz0 = 1.f - wz1;

    #define CORNER(ix, iy, iz) h2f(convb[(((ix) * VY + (iy)) * VZ + (iz)) * NC + co])
    float t = 0.f;
    t = fmaf(CORNER(ix0, iy0, iz0), wx0 * wy0 * wz0, t);
    t = fmaf(CORNER(ix0, iy0, iz1), wx0 * wy0 * wz1, t);
    t = fmaf(CORNER(ix0, iy1, iz0), wx0 * wy1 * wz0, t);
    t = fmaf(CORNER(ix0, iy1, iz1), wx0 * wy1 * wz1, t);
    t = fmaf(CORNER(ix1, iy0, iz0), wx1 * wy0 * wz0, t);
    t = fmaf(CORNER(ix1, iy0, iz1), wx1 * wy0 * wz1, t);
    t = fmaf(CORNER(ix1, iy1, iz0), wx1 * wy1 * wz0, t);
    t = fmaf(CORNER(ix1, iy1, iz1), wx1 * wy1 * wz1, t);
    #undef CORNER

    out[p * NC + co] = mlp + t;
}

extern "C" void kernel_launch(void* const* d_in, const int* in_sizes, int n_in,
                              void* d_out, int out_size, void* d_ws, size_t ws_size,
                              hipStream_t stream) {
    const float* inputs    = (const float*)d_in[0];
    const float* pt_coords = (const float*)d_in[1];
    const float* ppv_inv   = (const float*)d_in[2];
    const float* W_mlp     = (const float*)d_in[3];
    const float* b_mlp     = (const float*)d_in[4];
    const float* gamma1    = (const float*)d_in[5];
    const float* beta1     = (const float*)d_in[6];
    const float* mean1     = (const float*)d_in[7];
    const float* var1      = (const float*)d_in[8];
    const float* conv_w    = (const float*)d_in[9];
    const float* conv_b    = (const float*)d_in[10];
    const float* gamma2    = (const float*)d_in[11];
    const float* beta2     = (const float*)d_in[12];
    const float* mean2     = (const float*)d_in[13];
    const float* var2      = (const float*)d_in[14];
    const int*   vidx      = (const int*)d_in[15];

    const size_t NVOX = (size_t)VX * VY * VZ;                // 819,200
    char* ws = (char*)d_ws;
    u16* vox   = (u16*)ws;                                   // 104,857,600 B (f16 scaled grid)
    u16* convo = (u16*)(ws + NVOX * NC * 2);                 // 104,857,600 B (f16 conv out)
    u16* wT    = (u16*)(ws + 2 * NVOX * NC * 2);             // 221,184 B
    float* out = (float*)d_out;

    hipMemsetAsync(vox, 0, NVOX * NC * 2, stream);
    k_wt<<<432, 256, 0, stream>>>(conv_w, wT);
    k_scatter<<<(NPTS * 16) / 256, 256, 0, stream>>>(inputs, ppv_inv, vidx, (u64*)vox);
    k_conv<<<VX * (VY / YB), 256, 0, stream>>>(vox, wT, conv_b, gamma2, beta2, mean2, var2, convo);
    k_final<<<NPTS / 4, 256, 0, stream>>>(inputs, pt_coords, W_mlp, b_mlp,
                                          gamma1, beta1, mean1, var1, convo, out);
}

// Round 19
// 485.498 us; speedup vs baseline: 1.9148x; 1.1044x over previous
//
#include <hip/hip_runtime.h>
#include <hip/hip_bf16.h>
#include <hip/hip_fp16.h>

#define VX 160
#define VY 160
#define VZ 32
#define NC 64
#define NPTS 200000
#define BN_EPS 1e-3f
#define YB 4                      // y-columns per conv block
#define SLAB_ROWS ((YB + 2) * 34) // 204 rows (y-major, z-padded)

typedef __attribute__((ext_vector_type(4))) float f32x4;
typedef __attribute__((ext_vector_type(8))) _Float16 f16x8;
typedef unsigned short u16;
typedef unsigned long long u64;

__device__ __forceinline__ float h2f(u16 u) {
    union { u16 s; _Float16 h; } v; v.s = u; return (float)v.h;
}
__device__ __forceinline__ u16 f2h(float f) {
    union { u16 s; _Float16 h; } v; v.h = (_Float16)f; return v.s;
}

// ------------------------------------------- scatter-mean (scaled) into f16 grid
// Fast path: inv[v]==1.0f <=> exactly one point in voxel v <=> sole writer ->
// plain 8B store (no atomic). ~89% of points. Multi-point voxels use CAS.
__global__ __launch_bounds__(256) void k_scatter(const float* __restrict__ in,
                                                 const float* __restrict__ inv,
                                                 const int* __restrict__ vidx,
                                                 u64* __restrict__ vox) {
    int t = blockIdx.x * 256 + threadIdx.x;     // t < NPTS*16 exactly
    int n = t >> 4, q = t & 15;
    int vx = vidx[n * 3 + 0], vy = vidx[n * 3 + 1], vz = vidx[n * 3 + 2];
    int v = (vx * VY + vy) * VZ + vz;
    float s = inv[v];
    float4 a = *(const float4*)&in[n * NC + q * 4];
    float av0 = a.x * s, av1 = a.y * s, av2 = a.z * s, av3 = a.w * s;
    u64* addr = &vox[(size_t)v * 16 + q];
    union { u64 u; u16 h[4]; } pk;
    pk.h[0] = f2h(av0); pk.h[1] = f2h(av1); pk.h[2] = f2h(av2); pk.h[3] = f2h(av3);
    if (s == 1.0f) {                            // singleton voxel: sole writer
        *addr = pk.u;
        return;
    }
    u64 old = 0ull, assumed;
    do {
        assumed = old;
        union { u64 u; u16 h[4]; } cur, nxt;
        cur.u = assumed;
        nxt.h[0] = f2h(h2f(cur.h[0]) + av0);
        nxt.h[1] = f2h(h2f(cur.h[1]) + av1);
        nxt.h[2] = f2h(h2f(cur.h[2]) + av2);
        nxt.h[3] = f2h(h2f(cur.h[3]) + av3);
        old = atomicCAS(addr, assumed, nxt.u);
    } while (old != assumed);
}

// --------- weights: conv f32 [tap][ci][co] -> f16 [tap][co][ci]; MLP W -> f16 [co][ci]
__global__ __launch_bounds__(256) void k_wt(const float* __restrict__ w,
                                            const float* __restrict__ wm,
                                            u16* __restrict__ wT,
                                            u16* __restrict__ Wh) {
    int t = blockIdx.x * 256 + threadIdx.x;
    if (t < 27 * NC * NC) {
        int tap = t / (NC * NC), r = t % (NC * NC);
        int co = r / NC, ci = r % NC;
        wT[t] = f2h(w[(tap * NC + ci) * NC + co]);
    } else if (t < 27 * NC * NC + NC * NC) {
        int i = t - 27 * NC * NC;
        int co = i >> 6, ci = i & 63;
        Wh[i] = f2h(wm[ci * NC + co]);
    }
}

#define MFMA16(a, b, c) __builtin_amdgcn_mfma_f32_16x16x32_f16((a), (b), (c), 0, 0, 0)

// ---------------------------------------------------------------- conv3d MFMA
// r13 champion, verbatim. Thin-wave (r11) + deep A-prefetch: all 8 A-fragments
// of a tap issued back-to-back before the 16-MFMA burst. VGPR 88, 26.1KB LDS.
__global__ __launch_bounds__(256, 2) void k_conv(const u16* __restrict__ vox,
                                                 const u16* __restrict__ wT,
                                                 const float* __restrict__ bias,
                                                 const float* __restrict__ g2,
                                                 const float* __restrict__ b2,
                                                 const float* __restrict__ m2,
                                                 const float* __restrict__ v2,
                                                 u16* __restrict__ outb) {
    __shared__ __align__(16) u16 tile[SLAB_ROWS * 64];   // 26,112 B
    // XCD-aware bijective swizzle: 6400 = 8 XCDs x 800
    int bx0 = blockIdx.x;
    int bx = (bx0 & 7) * 800 + (bx0 >> 3);
    int x = bx / (VY / YB), y0 = (bx % (VY / YB)) * YB;
    int tid = threadIdx.x;
    int wave = tid >> 6, l = tid & 63;
    int yw = (wave >> 1) * 2;            // local y base of this wave (0 or 2)
    int nh = wave & 1;                   // co half (0/1)
    int lr = l & 15;
    int kg = l >> 4;                     // 0..3

    f32x4 acc[4][2];
    #pragma unroll
    for (int m = 0; m < 4; ++m)
        #pragma unroll
        for (int nt = 0; nt < 2; ++nt) acc[m][nt] = (f32x4){0.f, 0.f, 0.f, 0.f};

    // prefetch B for tap 0 (q = nt*2 + kf)
    f16x8 bc[4], bn[4];
    #pragma unroll
    for (int q = 0; q < 4; ++q)
        bc[q] = *(const f16x8*)&wT[(nh * 32 + (q >> 1) * 16 + lr) * NC + (q & 1) * 32 + kg * 8];

    for (int cx = 0; cx < 3; ++cx) {
        __syncthreads();                 // protect previous slab reads
        int xx = x + cx - 1;
        bool xok = (unsigned)xx < VX;
        #pragma unroll
        for (int i = 0; i < 7; ++i) {    // ceil(204*8 / 256) = 7
            int G = tid + i * 256;
            if (G < SLAB_ROWS * 8) {
                int r = G >> 3, g = G & 7;
                int yl = r / 34, zp = r - yl * 34;
                int y = y0 + yl - 1;
                uint4 val = make_uint4(0u, 0u, 0u, 0u);
                if (xok && zp >= 1 && zp <= 32 && (unsigned)y < VY)
                    val = *(const uint4*)&vox[(size_t)(((xx * VY) + y) * VZ + (zp - 1)) * NC + g * 8];
                *(uint4*)&tile[r * 64 + (g ^ (r & 7)) * 8] = val;
            }
        }
        __syncthreads();

        #pragma unroll
        for (int t9 = 0; t9 < 9; ++t9) {
            const int dy = t9 / 3, dz = t9 % 3;          // constants (unrolled)
            bool more = (cx < 2) || (t9 < 8);
            if (more) {
                const u16* wb = &wT[(cx * 9 + t9 + 1) * (NC * NC)];
                #pragma unroll
                for (int q = 0; q < 4; ++q)
                    bn[q] = *(const f16x8*)&wb[(nh * 32 + (q >> 1) * 16 + lr) * NC + (q & 1) * 32 + kg * 8];
            }
            int rbase = (yw + dy) * 34 + lr + dz;
            // deep A-prefetch: all 8 fragments issued back-to-back
            f16x8 a[8];
            #pragma unroll
            for (int m = 0; m < 4; ++m) {                // rn = rbase + jy*34 + zh*16
                int rn = rbase + (m >> 1) * 34 + (m & 1) * 16;
                int sw = rn & 7;
                a[2 * m]     = *(const f16x8*)&tile[rn * 64 + ((kg ^ sw) * 8)];
                a[2 * m + 1] = *(const f16x8*)&tile[rn * 64 + (((4 + kg) ^ sw) * 8)];
            }
            #pragma unroll
            for (int m = 0; m < 4; ++m) {
                acc[m][0] = MFMA16(a[2 * m],     bc[0], acc[m][0]);
                acc[m][0] = MFMA16(a[2 * m + 1], bc[1], acc[m][0]);
                acc[m][1] = MFMA16(a[2 * m],     bc[2], acc[m][1]);
                acc[m][1] = MFMA16(a[2 * m + 1], bc[3], acc[m][1]);
            }
            if (more) {
                #pragma unroll
                for (int q = 0; q < 4; ++q) bc[q] = bn[q];
            }
        }
    }

    // ---------------- epilogue: BN fold, stage f16 result in LDS, coalesced store
    float s[2], o[2], bb[2];
    #pragma unroll
    for (int nt = 0; nt < 2; ++nt) {
        int co = nh * 32 + nt * 16 + lr;
        s[nt] = g2[co] * rsqrtf(v2[co] + BN_EPS);
        o[nt] = b2[co] - m2[co] * s[nt];
        bb[nt] = bias[co];
    }
    __syncthreads();                     // all slab reads done; reuse tile
    #pragma unroll
    for (int m = 0; m < 4; ++m) {
        int jy = m >> 1, zh = m & 1;
        int yl = yw + jy;                // 0..3
        #pragma unroll
        for (int nt = 0; nt < 2; ++nt) {
            int co = nh * 32 + nt * 16 + lr;
            #pragma unroll
            for (int rr = 0; rr < 4; ++rr) {
                int z = zh * 16 + kg * 4 + rr;       // D row = (lane>>4)*4 + reg
                tile[(yl * 32 + z) * 64 + co] =
                    f2h(fmaxf(acc[m][nt][rr] + bb[nt], 0.f) * s[nt] + o[nt]);
            }
        }
    }
    __syncthreads();
    u16* ob = &outb[(size_t)((x * VY + y0) * VZ) * NC];
    #pragma unroll
    for (int i = 0; i < 4; ++i) {        // 4y*32z*64c*2B = 16 KB, fully coalesced
        int idx = tid + i * 256;
        *(uint4*)&ob[idx * 8] = *(const uint4*)&tile[idx * 8];
    }
}

// --------------------------------------- MFMA MLP + BN1 + trilinear devox + add
// Block = 64 points. Phase 1: stage in -> f16 LDS (XOR-swizzled groups).
// Phase 2: 4 waves x (4 m-tiles x K=64) MFMA -> BN1 -> f32 LDS.
// Phase 3: gather (identical memory pattern to the old k_final: co = lane,
// 128B coalesced corner reads), 16 points per thread.
__global__ __launch_bounds__(256) void k_final(const float* __restrict__ in,
                                               const float* __restrict__ pts,
                                               const u16* __restrict__ Wh,
                                               const float* __restrict__ bm,
                                               const float* __restrict__ g1,
                                               const float* __restrict__ be1,
                                               const float* __restrict__ m1,
                                               const float* __restrict__ v1,
                                               const u16* __restrict__ convb,
                                               float* __restrict__ out) {
    __shared__ __align__(16) u16 inh[64 * 64];       // 8,192 B
    __shared__ __align__(16) float mlpb[64 * 64];    // 16,384 B
    int tid = threadIdx.x;
    size_t pbase = (size_t)blockIdx.x * 64;          // 3125 blocks x 64 points

    // phase 1: stage+convert 16KB of inputs (each thread: 16 f32 -> 2 uint4)
    {
        const float* src = in + pbase * NC + tid * 16;
        float4 v0 = *(const float4*)(src);
        float4 v1 = *(const float4*)(src + 4);
        float4 v2 = *(const float4*)(src + 8);
        float4 v3 = *(const float4*)(src + 12);
        int pt = tid >> 2, gb = (tid & 3) * 2, sw = pt & 7;
        union { uint4 u; u16 h[8]; } pk;
        pk.h[0] = f2h(v0.x); pk.h[1] = f2h(v0.y); pk.h[2] = f2h(v0.z); pk.h[3] = f2h(v0.w);
        pk.h[4] = f2h(v1.x); pk.h[5] = f2h(v1.y); pk.h[6] = f2h(v1.z); pk.h[7] = f2h(v1.w);
        *(uint4*)&inh[pt * 64 + ((gb ^ sw) * 8)] = pk.u;
        pk.h[0] = f2h(v2.x); pk.h[1] = f2h(v2.y); pk.h[2] = f2h(v2.z); pk.h[3] = f2h(v2.w);
        pk.h[4] = f2h(v3.x); pk.h[5] = f2h(v3.y); pk.h[6] = f2h(v3.z); pk.h[7] = f2h(v3.w);
        *(uint4*)&inh[pt * 64 + (((gb + 1) ^ sw) * 8)] = pk.u;
    }
    int wave = tid >> 6, l = tid & 63, lr = l & 15, kg = l >> 4;
    int co = wave * 16 + lr;             // this wave's co-tile
    f16x8 b0 = *(const f16x8*)&Wh[co * 64 + kg * 8];
    f16x8 b1 = *(const f16x8*)&Wh[co * 64 + 32 + kg * 8];
    __syncthreads();

    // phase 2: MFMA over M=64 points, K=64
    f32x4 acc[4];
    #pragma unroll
    for (int mt = 0; mt < 4; ++mt) {
        int pt = mt * 16 + lr, sw = lr & 7;
        f16x8 a0 = *(const f16x8*)&inh[pt * 64 + ((kg ^ sw) * 8)];
        f16x8 a1 = *(const f16x8*)&inh[pt * 64 + (((4 + kg) ^ sw) * 8)];
        acc[mt] = (f32x4){0.f, 0.f, 0.f, 0.f};
        acc[mt] = MFMA16(a0, b0, acc[mt]);
        acc[mt] = MFMA16(a1, b1, acc[mt]);
    }
    float s1 = g1[co] * rsqrtf(v1[co] + BN_EPS);
    float o1 = be1[co] - m1[co] * s1;
    float bb = bm[co];
    #pragma unroll
    for (int mt = 0; mt < 4; ++mt)
        #pragma unroll
        for (int rr = 0; rr < 4; ++rr)   // D row = (lane>>4)*4 + reg
            mlpb[(mt * 16 + kg * 4 + rr) * 64 + co] =
                fmaxf(acc[mt][rr] + bb, 0.f) * s1 + o1;
    __syncthreads();

    // phase 3: trilinear gather + add (wave w owns points w*16..w*16+15)
    int co2 = l;
    #pragma unroll 2
    for (int j = 0; j < 16; ++j) {
        int pl = wave * 16 + j;
        size_t p = pbase + pl;
        float px = fminf(fmaxf(pts[p * 3 + 0], 0.f), (float)(VX - 1));
        float py = fminf(fmaxf(pts[p * 3 + 1], 0.f), (float)(VY - 1));
        float pz = fminf(fmaxf(pts[p * 3 + 2], 0.f), (float)(VZ - 1));
        float fx = floorf(px), fy = floorf(py), fz = floorf(pz);
        int ix0 = (int)fx, iy0 = (int)fy, iz0 = (int)fz;
        int ix1 = min(ix0 + 1, VX - 1), iy1 = min(iy0 + 1, VY - 1), iz1 = min(iz0 + 1, VZ - 1);
        float wx1 = px - fx, wy1 = py - fy, wz1 = pz - fz;
        float wx0 = 1.f - wx1, wy0 = 1.f - wy1, wz0 = 1.f - wz1;

        #define CORNER(ix, iy, iz) h2f(convb[(((ix) * VY + (iy)) * VZ + (iz)) * NC + co2])
        float t = 0.f;
        t = fmaf(CORNER(ix0, iy0, iz0), wx0 * wy0 * wz0, t);
        t = fmaf(CORNER(ix0, iy0, iz1), wx0 * wy0 * wz1, t);
        t = fmaf(CORNER(ix0, iy1, iz0), wx0 * wy1 * wz0, t);
        t = fmaf(CORNER(ix0, iy1, iz1), wx0 * wy1 * wz1, t);
        t = fmaf(CORNER(ix1, iy0, iz0), wx1 * wy0 * wz0, t);
        t = fmaf(CORNER(ix1, iy0, iz1), wx1 * wy0 * wz1, t);
        t = fmaf(CORNER(ix1, iy1, iz0), wx1 * wy1 * wz0, t);
        t = fmaf(CORNER(ix1, iy1, iz1), wx1 * wy1 * wz1, t);
        #undef CORNER

        out[p * NC + co2] = mlpb[pl * 64 + co2] + t;
    }
}

extern "C" void kernel_launch(void* const* d_in, const int* in_sizes, int n_in,
                              void* d_out, int out_size, void* d_ws, size_t ws_size,
                              hipStream_t stream) {
    const float* inputs    = (const float*)d_in[0];
    const float* pt_coords = (const float*)d_in[1];
    const float* ppv_inv   = (const float*)d_in[2];
    const float* W_mlp     = (const float*)d_in[3];
    const float* b_mlp     = (const float*)d_in[4];
    const float* gamma1    = (const float*)d_in[5];
    const float* beta1     = (const float*)d_in[6];
    const float* mean1     = (const float*)d_in[7];
    const float* var1      = (const float*)d_in[8];
    const float* conv_w    = (const float*)d_in[9];
    const float* conv_b    = (const float*)d_in[10];
    const float* gamma2    = (const float*)d_in[11];
    const float* beta2     = (const float*)d_in[12];
    const float* mean2     = (const float*)d_in[13];
    const float* var2      = (const float*)d_in[14];
    const int*   vidx      = (const int*)d_in[15];

    const size_t NVOX = (size_t)VX * VY * VZ;                // 819,200
    char* ws = (char*)d_ws;
    u16* vox   = (u16*)ws;                                   // 104,857,600 B (f16 scaled grid)
    u16* convo = (u16*)(ws + NVOX * NC * 2);                 // 104,857,600 B (f16 conv out)
    u16* wT    = (u16*)(ws + 2 * NVOX * NC * 2);             // 221,184 B
    u16* Wh    = (u16*)(ws + 2 * NVOX * NC * 2 + 221184);    // 8,192 B (MLP W f16 [co][ci])
    float* out = (float*)d_out;

    hipMemsetAsync(vox, 0, NVOX * NC * 2, stream);
    k_wt<<<448, 256, 0, stream>>>(conv_w, W_mlp, wT, Wh);
    k_scatter<<<(NPTS * 16) / 256, 256, 0, stream>>>(inputs, ppv_inv, vidx, (u64*)vox);
    k_conv<<<VX * (VY / YB), 256, 0, stream>>>(vox, wT, conv_b, gamma2, beta2, mean2, var2, convo);
    k_final<<<NPTS / 64, 256, 0, stream>>>(inputs, pt_coords, Wh, b_mlp,
                                           gamma1, beta1, mean1, var1, convo, out);
}